// Round 6
// baseline (767.099 us; speedup 1.0000x reference)
//
#include <hip/hip_runtime.h>

#define NTOK 8192
#define DDIM 1024
#define HDIM 2048
#define NEXP 8
#define GEXP 2                  // experts per group (h' = 67 MB, L3-resident)

typedef unsigned short u16;
typedef short bf16x8 __attribute__((ext_vector_type(8)));
typedef float f32x4 __attribute__((ext_vector_type(4)));
typedef float float4_t __attribute__((ext_vector_type(4)));

__device__ __forceinline__ u16 f2bf(float f) {
  unsigned u = __float_as_uint(f);
  u += 0x7FFFu + ((u >> 16) & 1u);   // round-to-nearest-even
  return (u16)(u >> 16);
}

#define GLOAD_LDS16(gp, lp)                                                     \
  __builtin_amdgcn_global_load_lds(                                             \
      (const __attribute__((address_space(1))) unsigned int*)(gp),              \
      (__attribute__((address_space(3))) unsigned int*)(lp), 16, 0, 0)

// ------------------------------------------------ fused x->bf16 convert + gate
__global__ void k_prep(const float* __restrict__ x, const float* __restrict__ Wg,
                       const float* __restrict__ bg,
                       u16* __restrict__ xb, float* __restrict__ gate) {
  const int tok = (blockIdx.x * 256 + threadIdx.x) >> 6;
  const int lane = threadIdx.x & 63;
  const float* xr = x + (size_t)tok * DDIM;
  u16* xo = xb + (size_t)tok * DDIM;
  float s[NEXP];
#pragma unroll
  for (int e = 0; e < NEXP; ++e) s[e] = 0.f;
#pragma unroll
  for (int it = 0; it < 2; ++it) {
    const int d0 = lane * 8 + it * 512;
    float4_t v0 = *(const float4_t*)(xr + d0);
    float4_t v1 = *(const float4_t*)(xr + d0 + 4);
    union { bf16x8 v; u16 h[8]; } u;
    u.h[0] = f2bf(v0.x); u.h[1] = f2bf(v0.y); u.h[2] = f2bf(v0.z); u.h[3] = f2bf(v0.w);
    u.h[4] = f2bf(v1.x); u.h[5] = f2bf(v1.y); u.h[6] = f2bf(v1.z); u.h[7] = f2bf(v1.w);
    *(bf16x8*)(xo + d0) = u.v;
    float xv[8] = {v0.x, v0.y, v0.z, v0.w, v1.x, v1.y, v1.z, v1.w};
#pragma unroll
    for (int j = 0; j < 8; ++j) {
      const float4_t w0 = *(const float4_t*)(Wg + (size_t)(d0 + j) * NEXP);
      const float4_t w1 = *(const float4_t*)(Wg + (size_t)(d0 + j) * NEXP + 4);
      s[0] += xv[j] * w0.x; s[1] += xv[j] * w0.y;
      s[2] += xv[j] * w0.z; s[3] += xv[j] * w0.w;
      s[4] += xv[j] * w1.x; s[5] += xv[j] * w1.y;
      s[6] += xv[j] * w1.z; s[7] += xv[j] * w1.w;
    }
  }
#pragma unroll
  for (int off = 32; off; off >>= 1)
#pragma unroll
    for (int e = 0; e < NEXP; ++e) s[e] += __shfl_down(s[e], off);
  if (lane == 0) {
#pragma unroll
    for (int e = 0; e < NEXP; ++e) gate[(size_t)tok * NEXP + e] = s[e] + bg[e];
  }
}

// ------------- vectorized transpose+convert: out[z*oexp + c*orstride + r] = in[z][r][c]
__global__ void k_transpose(const float* __restrict__ in, u16* __restrict__ out,
                            int R, int C, size_t oexp, int orstride) {
  __shared__ float t[64][65];
  const int rb = blockIdx.x * 64, cb = blockIdx.y * 64;
  const float* pin = in + (size_t)blockIdx.z * R * C;
  u16* pout = out + (size_t)blockIdx.z * oexp;
  const int tid = threadIdx.x;
  {
    const int r = tid >> 4;
    const int c4 = (tid & 15) * 4;
#pragma unroll
    for (int i = 0; i < 4; ++i) {
      float4_t v = *(const float4_t*)(pin + (size_t)(rb + r + 16 * i) * C + cb + c4);
      t[r + 16 * i][c4 + 0] = v.x;
      t[r + 16 * i][c4 + 1] = v.y;
      t[r + 16 * i][c4 + 2] = v.z;
      t[r + 16 * i][c4 + 3] = v.w;
    }
  }
  __syncthreads();
  {
    const int oc = tid >> 3;
    const int r8 = (tid & 7) * 8;
#pragma unroll
    for (int jp = 0; jp < 2; ++jp) {
      const int ocol = oc + 32 * jp;
      union { bf16x8 v; u16 h[8]; } u;
#pragma unroll
      for (int k = 0; k < 8; ++k) u.h[k] = f2bf(t[r8 + k][ocol]);
      *(bf16x8*)(pout + (size_t)(cb + ocol) * orstride + rb + r8) = u.v;
    }
  }
}

// =================== 8-phase GEMM (quadrant phases, counted vmcnt, T2+T3+T4+T5)
// C[TBM-tiles][256-tiles] = A[M][K] * B^T ; BCH: B in per-expert blocks, K chunked
// MODE 1: h' = bf16(gate*relu(acc+bias)) ; MODE 2: out f32 (+)= acc (+gate.b2)
// 8 waves = 2M x 4N; per K-tile: 4 phases (mh,nh), 16(or 8) MFMA each;
// stage 1 half-tile per phase, 5-6 phases ahead of its consumption;
// vmcnt(AH+BH loads) once per K-tile boundary (never 0 except final tile).
template <int MODE, int BCH, int TBM>
__global__ __launch_bounds__(512, 2) void k_gemm8(
    const u16* __restrict__ A, int lda,
    const u16* __restrict__ Bt, int ldb,
    const float* __restrict__ bias,
    const float* __restrict__ gate, int ebase,
    void* __restrict__ Cout, int ldc,
    int tilesN, int K, int accum, int ca, int cb) {
  constexpr int MREPH = TBM / 64;       // M-frags per phase (256->4, 128->2)
  constexpr int AH = TBM / 128;         // glds per A-half (2 or 1)
  __shared__ __align__(16) u16 lds[2 * (TBM + 256) * 64];   // 128 / 96 KiB
  const int tid = threadIdx.x;
  const int lane = tid & 63;
  const int wid = tid >> 6;             // 0..7
  const int wm = wid >> 2;              // 0..1
  const int wn = wid & 3;               // 0..3
  const int wmr = wm * (TBM / 4);
  const int wnr = wn * 32;

  // supertiled XCD-aware ordering (grid == 8*ca*cb)
  int wg = blockIdx.x;
  int xcd = wg & 7, lo = wg >> 3;
  int cgcols = tilesN / cb;
  int cr = xcd / cgcols, cc = xcd % cgcols;
  int tm = cr * ca + lo / cb;
  int tn = cc * cb + lo % cb;
  int bm = tm * TBM, bn = tn * 256;

  // staging: linear LDS dest + inverse-swizzled global source (rule 21)
  const int srow = tid >> 3;                        // 0..63
  const int scol = ((tid & 7) ^ (srow & 7)) << 3;   // swizzled col (elems)
  const u16* gA = A + (size_t)(bm + srow) * lda + scol;
  const u16* gB = Bt + (size_t)(bn + srow) * ldb + scol;
  const int dofs = wid * 512;

  u16* aB0 = lds;
  u16* bB0 = lds + TBM * 64;
  u16* aB1 = lds + (TBM + 256) * 64;
  u16* bB1 = aB1 + TBM * 64;

#define BOFF(kt) (BCH ? ((size_t)((kt) >> 5) * ((size_t)DDIM * HDIM) +          \
                         (size_t)((kt) & 31) * 64)                              \
                      : (size_t)(kt) * 64)
#define STG_A(dst, hh, ts)                                                      \
  { _Pragma("unroll") for (int j_ = 0; j_ < AH; ++j_)                           \
      GLOAD_LDS16(gA + (size_t)((hh) * (TBM / 2) + j_ * 64) * lda +             \
                      (size_t)(ts) * 64,                                        \
                  (dst) + ((hh) * (TBM / 2) + j_ * 64) * 64 + dofs); }
#define STG_B(dst, hh, ts)                                                      \
  { _Pragma("unroll") for (int j_ = 0; j_ < 2; ++j_)                            \
      GLOAD_LDS16(gB + (size_t)((hh) * 128 + j_ * 64) * ldb + BOFF(ts),         \
                  (dst) + ((hh) * 128 + j_ * 64) * 64 + dofs); }
#define VMC_N()                                                                 \
  { if (TBM == 256) asm volatile("s_waitcnt vmcnt(4)" ::: "memory");            \
    else            asm volatile("s_waitcnt vmcnt(3)" ::: "memory"); }

  // fragment read offsets (swizzled)
  const int fr = lane & 15;
  const int fq = lane >> 4;
  const int xr = fr & 7;
  const int so0 = ((0 + fq) ^ xr) << 3;
  const int so1 = ((4 + fq) ^ xr) << 3;

  f32x4 acc[4][MREPH][2] = {};

  // quadrant phase: ds_read 12 (8 A + 4 B), barrier, MFMA cluster, (caller barrier)
#define QPHASE(MH, NH, aCur, bCur)                                              \
  {                                                                             \
    bf16x8 av[MREPH][2], bv[2][2];                                              \
    _Pragma("unroll") for (int i_ = 0; i_ < MREPH; ++i_) {                      \
      const int rb_ = ((MH) * (TBM / 2) + wmr + i_ * 16 + fr) << 6;             \
      av[i_][0] = *(const bf16x8*)((aCur) + rb_ + so0);                         \
      av[i_][1] = *(const bf16x8*)((aCur) + rb_ + so1);                         \
    }                                                                           \
    _Pragma("unroll") for (int n_ = 0; n_ < 2; ++n_) {                          \
      const int rb_ = ((NH) * 128 + wnr + n_ * 16 + fr) << 6;                   \
      bv[n_][0] = *(const bf16x8*)((bCur) + rb_ + so0);                         \
      bv[n_][1] = *(const bf16x8*)((bCur) + rb_ + so1);                         \
    }                                                                           \
    __builtin_amdgcn_s_barrier();                                               \
    asm volatile("s_waitcnt lgkmcnt(0)" ::: "memory");                          \
    __builtin_amdgcn_sched_barrier(0);                                          \
    __builtin_amdgcn_s_setprio(1);                                              \
    _Pragma("unroll") for (int i_ = 0; i_ < MREPH; ++i_)                        \
      _Pragma("unroll") for (int n_ = 0; n_ < 2; ++n_) {                        \
        acc[(MH) * 2 + (NH)][i_][n_] = __builtin_amdgcn_mfma_f32_16x16x32_bf16( \
            av[i_][0], bv[n_][0], acc[(MH) * 2 + (NH)][i_][n_], 0, 0, 0);       \
        acc[(MH) * 2 + (NH)][i_][n_] = __builtin_amdgcn_mfma_f32_16x16x32_bf16( \
            av[i_][1], bv[n_][1], acc[(MH) * 2 + (NH)][i_][n_], 0, 0, 0);       \
      }                                                                         \
    __builtin_amdgcn_s_setprio(0);                                              \
  }

  const int nkt = K >> 6;   // >= 2 always here

  // prologue: tile0 all 4 halves -> buf0; tile1 A0,B0 -> buf1; keep last 2 in flight
  STG_A(aB0, 0, 0); STG_B(bB0, 0, 0); STG_A(aB0, 1, 0); STG_B(bB0, 1, 0);
  STG_A(aB1, 0, 1); STG_B(bB1, 0, 1);
  VMC_N();
  __builtin_amdgcn_s_barrier();

  u16 *aC_ = aB0, *bC_ = bB0, *aN_ = aB1, *bN_ = bB1;

#pragma unroll 1
  for (int t = 0; t < nkt; ++t) {
    const bool s1ok = (t + 1 < nkt);
    const bool s2ok = (t + 2 < nkt);
    // phase q=0 (mh0,nh0): stage A1(t+1) -> next buf
    if (s1ok) STG_A(aN_, 1, t + 1);
    QPHASE(0, 0, aC_, bC_);
    __builtin_amdgcn_s_barrier();
    // phase q=1 (mh0,nh1): stage B1(t+1) -> next buf
    if (s1ok) STG_B(bN_, 1, t + 1);
    QPHASE(0, 1, aC_, bC_);
    __builtin_amdgcn_s_barrier();
    // phase q=2 (mh1,nh0): stage A0(t+2) -> cur buf (A0 readers done at q=1 barrier)
    if (s2ok) STG_A(aC_, 0, t + 2);
    QPHASE(1, 0, aC_, bC_);
    __builtin_amdgcn_s_barrier();
    // phase q=3 (mh1,nh1): stage B0(t+2) -> cur buf (B0 readers done at q=2 barrier)
    if (s2ok) STG_B(bC_, 0, t + 2);
    QPHASE(1, 1, aC_, bC_);
    if (s2ok) { VMC_N(); }                               // tile t+1 landed, 2 halves in flight
    else      { asm volatile("s_waitcnt vmcnt(0)" ::: "memory"); }
    __builtin_amdgcn_s_barrier();
    u16* tp;
    tp = aC_; aC_ = aN_; aN_ = tp;
    tp = bC_; bC_ = bN_; bN_ = tp;
  }

  // ---------------- epilogue; C/D layout: col=lane&15, row=(lane>>4)*4+j
  if (MODE == 1) {
    u16* O = (u16*)Cout;
#pragma unroll
    for (int q = 0; q < 4; ++q) {
      const int MH = q >> 1, NH = q & 1;
      const int cb0 = bn + NH * 128 + wnr;
      const int e = ebase + (cb0 >> 11);
      float bcol[2];
#pragma unroll
      for (int n = 0; n < 2; ++n) bcol[n] = bias[cb0 + n * 16 + fr];
#pragma unroll
      for (int i = 0; i < MREPH; ++i) {
#pragma unroll
        for (int j = 0; j < 4; ++j) {
          int r = bm + MH * (TBM / 2) + wmr + i * 16 + fq * 4 + j;
          float g = gate[(size_t)r * NEXP + e];
#pragma unroll
          for (int n = 0; n < 2; ++n) {
            float v = fmaxf(acc[q][i][n][j] + bcol[n], 0.f) * g;
            O[(size_t)r * ldc + cb0 + n * 16 + fr] = f2bf(v);
          }
        }
      }
    }
  } else {
    float* O = (float*)Cout;
    float b2c[2][2][NEXP];
    if (!accum) {
#pragma unroll
      for (int nh = 0; nh < 2; ++nh)
#pragma unroll
        for (int n = 0; n < 2; ++n)
#pragma unroll
          for (int e = 0; e < NEXP; ++e)
            b2c[nh][n][e] = bias[(size_t)e * DDIM + bn + nh * 128 + wnr + n * 16 + fr];
    }
#pragma unroll
    for (int q = 0; q < 4; ++q) {
      const int MH = q >> 1, NH = q & 1;
      const int cb0 = bn + NH * 128 + wnr;
#pragma unroll
      for (int i = 0; i < MREPH; ++i) {
#pragma unroll
        for (int j = 0; j < 4; ++j) {
          int r = bm + MH * (TBM / 2) + wmr + i * 16 + fq * 4 + j;
          if (!accum) {
            float g8[NEXP];
#pragma unroll
            for (int e = 0; e < NEXP; ++e) g8[e] = gate[(size_t)r * NEXP + e];
#pragma unroll
            for (int n = 0; n < 2; ++n) {
              float v = acc[q][i][n][j];
#pragma unroll
              for (int e = 0; e < NEXP; ++e) v += g8[e] * b2c[NH][n][e];
              O[(size_t)r * DDIM + cb0 + n * 16 + fr] = v;
            }
          } else {
#pragma unroll
            for (int n = 0; n < 2; ++n) {
              size_t idx = (size_t)r * DDIM + cb0 + n * 16 + fr;
              O[idx] += acc[q][i][n][j];
            }
          }
        }
      }
    }
  }
#undef QPHASE
#undef STG_A
#undef STG_B
#undef VMC_N
#undef BOFF
}

extern "C" void kernel_launch(void* const* d_in, const int* in_sizes, int n_in,
                              void* d_out, int out_size, void* d_ws, size_t ws_size,
                              hipStream_t stream) {
  (void)in_sizes; (void)n_in; (void)out_size;
  const float* x  = (const float*)d_in[0];   // [N, D]
  const float* W1 = (const float*)d_in[1];   // [E, D, H]
  const float* b1 = (const float*)d_in[2];   // [E, H]
  const float* W2 = (const float*)d_in[3];   // [E, H, D]
  const float* b2 = (const float*)d_in[4];   // [E, D]
  const float* Wg = (const float*)d_in[5];   // [D, E]
  const float* bg = (const float*)d_in[6];   // [E]
  float* out = (float*)d_out;                // [N, D]

  size_t o_xb   = 0;
  size_t o_w1t  = o_xb  + (size_t)NTOK * DDIM * 2;          // xb   bf16 [N,D]
  size_t o_w2t  = o_w1t + (size_t)NEXP * HDIM * DDIM * 2;   // W1t  bf16 [E*H, D]
  size_t o_gate = o_w2t + (size_t)NEXP * DDIM * HDIM * 2;   // W2t  bf16 [E][D][H]
  size_t o_h    = o_gate + (size_t)NTOK * NEXP * 4;         // gate f32  [N, E]
  size_t need   = o_h   + (size_t)NTOK * GEXP * HDIM * 2;   // h'   bf16 [N, G*H]
  if (ws_size < need) return;

  u16*   xb   = (u16*)((char*)d_ws + o_xb);
  u16*   W1t  = (u16*)((char*)d_ws + o_w1t);
  u16*   W2t  = (u16*)((char*)d_ws + o_w2t);
  float* gate = (float*)((char*)d_ws + o_gate);
  u16*   hbuf = (u16*)((char*)d_ws + o_h);

  k_prep<<<NTOK / 4, 256, 0, stream>>>(x, Wg, bg, xb, gate);
  dim3 g1(DDIM / 64, HDIM / 64, NEXP);
  k_transpose<<<g1, 256, 0, stream>>>(W1, W1t, DDIM, HDIM, (size_t)HDIM * DDIM, DDIM);
  dim3 g2(HDIM / 64, DDIM / 64, NEXP);
  k_transpose<<<g2, 256, 0, stream>>>(W2, W2t, HDIM, DDIM, (size_t)DDIM * HDIM, HDIM);

  const int Ng = GEXP * HDIM;                  // 4096
  for (int g = 0; g < NEXP / GEXP; ++g) {
    // GEMM1: 256x256 tiles, grid 32tm x 16tn = 512; XCD chunks 8x8
    k_gemm8<1, 0, 256><<<512, 512, 0, stream>>>(
        xb, DDIM, W1t + (size_t)g * Ng * DDIM, DDIM,
        b1 + (size_t)g * Ng, gate, g * GEXP,
        hbuf, Ng, Ng / 256, DDIM, 0, 8, 8);
    // GEMM2: 128x256 tiles, grid 64tm x 4tn = 256; XCD chunks 8x4
    k_gemm8<2, 1, 128><<<256, 512, 0, stream>>>(
        hbuf, Ng, W2t + (size_t)g * GEXP * DDIM * HDIM, HDIM,
        b2, gate, 0,
        out, DDIM, DDIM / 256, Ng, g > 0, 8, 4);
  }
}

// Round 7
// 628.764 us; speedup vs baseline: 1.2200x; 1.2200x over previous
//
#include <hip/hip_runtime.h>

#define NTOK 8192
#define DDIM 1024
#define HDIM 2048
#define NEXP 8
#define GEXP 2                  // experts per group
#define G1_NKT 16               // K=1024 / 64
#define G2_NKT 64               // K=4096 / 64

typedef unsigned short u16;
typedef short bf16x8 __attribute__((ext_vector_type(8)));
typedef float f32x4 __attribute__((ext_vector_type(4)));
typedef float float4_t __attribute__((ext_vector_type(4)));

__device__ __forceinline__ u16 f2bf(float f) {
  unsigned u = __float_as_uint(f);
  u += 0x7FFFu + ((u >> 16) & 1u);   // round-to-nearest-even
  return (u16)(u >> 16);
}

#define GLOAD_LDS16(gp, lp)                                                     \
  __builtin_amdgcn_global_load_lds(                                             \
      (const __attribute__((address_space(1))) unsigned int*)(gp),              \
      (__attribute__((address_space(3))) unsigned int*)(lp), 16, 0, 0)

#define VMW(n) asm volatile("s_waitcnt vmcnt(" #n ")" ::: "memory")
#define ENTRYB()                                                                \
  { __builtin_amdgcn_s_barrier(); __builtin_amdgcn_sched_barrier(0); }
#define LG0()                                                                   \
  { asm volatile("s_waitcnt lgkmcnt(0)" ::: "memory");                          \
    __builtin_amdgcn_sched_barrier(0); }

// ------------------------------------------------ fused x->bf16 convert + gate
__global__ void k_prep(const float* __restrict__ x, const float* __restrict__ Wg,
                       const float* __restrict__ bg,
                       u16* __restrict__ xb, float* __restrict__ gate) {
  const int tok = (blockIdx.x * 256 + threadIdx.x) >> 6;
  const int lane = threadIdx.x & 63;
  const float* xr = x + (size_t)tok * DDIM;
  u16* xo = xb + (size_t)tok * DDIM;
  float s[NEXP];
#pragma unroll
  for (int e = 0; e < NEXP; ++e) s[e] = 0.f;
#pragma unroll
  for (int it = 0; it < 2; ++it) {
    const int d0 = lane * 8 + it * 512;
    float4_t v0 = *(const float4_t*)(xr + d0);
    float4_t v1 = *(const float4_t*)(xr + d0 + 4);
    union { bf16x8 v; u16 h[8]; } u;
    u.h[0] = f2bf(v0.x); u.h[1] = f2bf(v0.y); u.h[2] = f2bf(v0.z); u.h[3] = f2bf(v0.w);
    u.h[4] = f2bf(v1.x); u.h[5] = f2bf(v1.y); u.h[6] = f2bf(v1.z); u.h[7] = f2bf(v1.w);
    *(bf16x8*)(xo + d0) = u.v;
    float xv[8] = {v0.x, v0.y, v0.z, v0.w, v1.x, v1.y, v1.z, v1.w};
#pragma unroll
    for (int j = 0; j < 8; ++j) {
      const float4_t w0 = *(const float4_t*)(Wg + (size_t)(d0 + j) * NEXP);
      const float4_t w1 = *(const float4_t*)(Wg + (size_t)(d0 + j) * NEXP + 4);
      s[0] += xv[j] * w0.x; s[1] += xv[j] * w0.y;
      s[2] += xv[j] * w0.z; s[3] += xv[j] * w0.w;
      s[4] += xv[j] * w1.x; s[5] += xv[j] * w1.y;
      s[6] += xv[j] * w1.z; s[7] += xv[j] * w1.w;
    }
  }
#pragma unroll
  for (int off = 32; off; off >>= 1)
#pragma unroll
    for (int e = 0; e < NEXP; ++e) s[e] += __shfl_down(s[e], off);
  if (lane == 0) {
#pragma unroll
    for (int e = 0; e < NEXP; ++e) gate[(size_t)tok * NEXP + e] = s[e] + bg[e];
  }
}

// ------------- vectorized transpose+convert: out[z*oexp + c*orstride + r] = in[z][r][c]
__global__ void k_transpose(const float* __restrict__ in, u16* __restrict__ out,
                            int R, int C, size_t oexp, int orstride) {
  __shared__ float t[64][65];
  const int rb = blockIdx.x * 64, cb = blockIdx.y * 64;
  const float* pin = in + (size_t)blockIdx.z * R * C;
  u16* pout = out + (size_t)blockIdx.z * oexp;
  const int tid = threadIdx.x;
  {
    const int r = tid >> 4;
    const int c4 = (tid & 15) * 4;
#pragma unroll
    for (int i = 0; i < 4; ++i) {
      float4_t v = *(const float4_t*)(pin + (size_t)(rb + r + 16 * i) * C + cb + c4);
      t[r + 16 * i][c4 + 0] = v.x;
      t[r + 16 * i][c4 + 1] = v.y;
      t[r + 16 * i][c4 + 2] = v.z;
      t[r + 16 * i][c4 + 3] = v.w;
    }
  }
  __syncthreads();
  {
    const int oc = tid >> 3;
    const int r8 = (tid & 7) * 8;
#pragma unroll
    for (int jp = 0; jp < 2; ++jp) {
      const int ocol = oc + 32 * jp;
      union { bf16x8 v; u16 h[8]; } u;
#pragma unroll
      for (int k = 0; k < 8; ++k) u.h[k] = f2bf(t[r8 + k][ocol]);
      *(bf16x8*)(pout + (size_t)(cb + ocol) * orstride + rb + r8) = u.v;
    }
  }
}

// ============ GEMM1: 256x256 tile, 4-phase snake, operand reuse, 1 barrier/phase
// h'[m][4096] = bf16(gate * relu(x . W1t^T + b1))
__global__ __launch_bounds__(512, 2) void k_g1(
    const u16* __restrict__ A, const u16* __restrict__ Bt,
    const float* __restrict__ bias, const float* __restrict__ gate,
    int ebase, u16* __restrict__ Cout) {
  __shared__ __align__(16) u16 lds[65536];   // 128 KiB: 2 buf x (A 256 | B 256) x 64
  const int tid = threadIdx.x, lane = tid & 63, wid = tid >> 6;
  const int wm = wid >> 2, wn = wid & 3;
  // XCD supertile: 32tm x 16tn grid; 8 chunks of 8x8, tn-inner
  const int wg = blockIdx.x;
  const int xcd = wg & 7, lo = wg >> 3;
  const int tm = (xcd >> 1) * 8 + (lo >> 3);
  const int tn = (xcd & 1) * 8 + (lo & 7);
  const int bm = tm * 256, bn = tn * 256;

  const int srow = tid >> 3;
  const int scol = ((tid & 7) ^ (srow & 7)) << 3;
  const u16* gA = A + (size_t)(bm + srow) * 1024 + scol;
  const u16* gB = Bt + (size_t)(bn + srow) * 1024 + scol;
  const int dofs = wid * 512;

  u16* aB0 = lds;          u16* bB0 = lds + 16384;
  u16* aB1 = lds + 32768;  u16* bB1 = lds + 49152;

  const int fr = lane & 15, fq = lane >> 4, xr = fr & 7;
  const int so0 = ((0 + fq) ^ xr) << 3;
  const int so1 = ((4 + fq) ^ xr) << 3;

  f32x4 acc[4][4][2] = {};
  bf16x8 av[4][2], bv[2][2];

#define G1_SA(dst, hh, ts)                                                      \
  { GLOAD_LDS16(gA + (size_t)((hh)*128     ) * 1024 + (size_t)(ts) * 64,        \
                (dst) + ((hh)*128     ) * 64 + dofs);                           \
    GLOAD_LDS16(gA + (size_t)((hh)*128 + 64) * 1024 + (size_t)(ts) * 64,        \
                (dst) + ((hh)*128 + 64) * 64 + dofs); }
#define G1_SB(dst, hh, ts)                                                      \
  { GLOAD_LDS16(gB + (size_t)((hh)*128     ) * 1024 + (size_t)(ts) * 64,        \
                (dst) + ((hh)*128     ) * 64 + dofs);                           \
    GLOAD_LDS16(gB + (size_t)((hh)*128 + 64) * 1024 + (size_t)(ts) * 64,        \
                (dst) + ((hh)*128 + 64) * 64 + dofs); }
#define RD_A(src, MH)                                                           \
  { _Pragma("unroll") for (int i_ = 0; i_ < 4; ++i_) {                          \
      const int rb_ = ((MH)*128 + wm * 64 + i_ * 16 + fr) << 6;                 \
      av[i_][0] = *(const bf16x8*)((src) + rb_ + so0);                          \
      av[i_][1] = *(const bf16x8*)((src) + rb_ + so1); } }
#define RD_B(src, NH)                                                           \
  { _Pragma("unroll") for (int n_ = 0; n_ < 2; ++n_) {                          \
      const int rb_ = ((NH)*128 + wn * 32 + n_ * 16 + fr) << 6;                 \
      bv[n_][0] = *(const bf16x8*)((src) + rb_ + so0);                          \
      bv[n_][1] = *(const bf16x8*)((src) + rb_ + so1); } }
#define MMA16(Q)                                                                \
  { __builtin_amdgcn_s_setprio(1);                                              \
    _Pragma("unroll") for (int i_ = 0; i_ < 4; ++i_)                            \
    _Pragma("unroll") for (int n_ = 0; n_ < 2; ++n_) {                          \
      acc[Q][i_][n_] = __builtin_amdgcn_mfma_f32_16x16x32_bf16(                 \
          av[i_][0], bv[n_][0], acc[Q][i_][n_], 0, 0, 0);                       \
      acc[Q][i_][n_] = __builtin_amdgcn_mfma_f32_16x16x32_bf16(                 \
          av[i_][1], bv[n_][1], acc[Q][i_][n_], 0, 0, 0); }                     \
    __builtin_amdgcn_s_setprio(0); }

  // prologue: tile0, issue order A0,B0,A1,B1 (matches steady-state order)
  G1_SA(aB0, 0, 0); G1_SB(bB0, 0, 0); G1_SA(aB0, 1, 0); G1_SB(bB0, 1, 0);

  u16 *aC_ = aB0, *bC_ = bB0, *aN_ = aB1, *bN_ = bB1;

#pragma unroll 1
  for (int t = 0; t < G1_NKT; ++t) {
    const bool s1 = (t + 1 < G1_NKT);
    // p0 = (M0,N0): needs A0(t),B0(t); stages A0(t+1)
    VMW(4); ENTRYB();
    RD_A(aC_, 0); RD_B(bC_, 0);
    if (s1) G1_SA(aN_, 0, t + 1);
    LG0(); MMA16(0);
    // p1 = (M1,N0): needs A1(t); B0 reused in regs; stages B0(t+1)
    if (s1) { VMW(4); } else { VMW(2); }
    ENTRYB();
    RD_A(aC_, 1);
    if (s1) G1_SB(bN_, 0, t + 1);
    LG0(); MMA16(2);
    // p2 = (M1,N1): needs B1(t); A1 reused; stages A1(t+1)
    if (s1) { VMW(4); } else { VMW(0); }
    ENTRYB();
    RD_B(bC_, 1);
    if (s1) G1_SA(aN_, 1, t + 1);
    LG0(); MMA16(3);
    // p3 = (M0,N1): re-reads A0(t) (stable); B1 reused; stages B1(t+1); NO barrier
    RD_A(aC_, 0);
    if (s1) G1_SB(bN_, 1, t + 1);
    LG0(); MMA16(1);
    u16* tp;
    tp = aC_; aC_ = aN_; aN_ = tp;
    tp = bC_; bC_ = bN_; bN_ = tp;
  }

  // epilogue; C/D layout: col=lane&15, row=(lane>>4)*4+j
#pragma unroll
  for (int q = 0; q < 4; ++q) {
    const int MH = q >> 1, NH = q & 1;
    const int cb0 = bn + NH * 128 + wn * 32;
    const int e = ebase + (cb0 >> 11);
    float bcol[2];
#pragma unroll
    for (int n = 0; n < 2; ++n) bcol[n] = bias[cb0 + n * 16 + fr];
#pragma unroll
    for (int i = 0; i < 4; ++i) {
#pragma unroll
      for (int j = 0; j < 4; ++j) {
        const int r = bm + MH * 128 + wm * 64 + i * 16 + fq * 4 + j;
        const float g = gate[(size_t)r * NEXP + e];
#pragma unroll
        for (int n = 0; n < 2; ++n) {
          float v = fmaxf(acc[q][i][n][j] + bcol[n], 0.f) * g;
          Cout[(size_t)r * (GEXP * HDIM) + cb0 + n * 16 + fr] = f2bf(v);
        }
      }
    }
  }
#undef G1_SA
#undef G1_SB
#undef RD_A
#undef RD_B
#undef MMA16
}

// ============ GEMM2: 128x256 tile, 2 fat phases (N-halves), A held in regs
// out[m][1024] (+)= h' . W2t^T  (+ sum_e gate*b2 when !accum)
__global__ __launch_bounds__(512, 2) void k_g2(
    const u16* __restrict__ A, const u16* __restrict__ Bt,
    const float* __restrict__ bias, const float* __restrict__ gate,
    float* __restrict__ Cout, int accum) {
  __shared__ __align__(16) u16 lds[49152];   // 96 KiB: 2 buf x (A 128 | B 256) x 64
  const int tid = threadIdx.x, lane = tid & 63, wid = tid >> 6;
  const int wm = wid >> 2, wn = wid & 3;
  // XCD supertile: 64tm x 4tn grid; 8 chunks of 8x4, tn-inner
  const int wg = blockIdx.x;
  const int xcd = wg & 7, lo = wg >> 3;
  const int tm = xcd * 8 + (lo >> 2);
  const int tn = lo & 3;
  const int bm = tm * 128, bn = tn * 256;

  const int srow = tid >> 3;
  const int scol = ((tid & 7) ^ (srow & 7)) << 3;
  const u16* gA = A + (size_t)(bm + srow) * (GEXP * HDIM) + scol;
  const u16* gB = Bt + (size_t)(bn + srow) * HDIM + scol;
  const int dofs = wid * 512;

  u16* aB0 = lds;          u16* bB0 = lds + 8192;
  u16* aB1 = lds + 24576;  u16* bB1 = lds + 32768;

  const int fr = lane & 15, fq = lane >> 4, xr = fr & 7;
  const int so0 = ((0 + fq) ^ xr) << 3;
  const int so1 = ((4 + fq) ^ xr) << 3;

  f32x4 acc[2][4][2] = {};
  bf16x8 av[4][2], bv[2][2];

#define G2_BOFF(ts) ((size_t)((ts) >> 5) * ((size_t)DDIM * HDIM) +              \
                     (size_t)((ts) & 31) * 64)
#define G2_SA(dst, ts)                                                          \
  { GLOAD_LDS16(gA + (size_t)(ts) * 64, (dst) + dofs);                          \
    GLOAD_LDS16(gA + (size_t)64 * (GEXP * HDIM) + (size_t)(ts) * 64,            \
                (dst) + 4096 + dofs); }
#define G2_SB(dst, hh, ts)                                                      \
  { GLOAD_LDS16(gB + (size_t)((hh)*128     ) * HDIM + G2_BOFF(ts),              \
                (dst) + ((hh)*128     ) * 64 + dofs);                           \
    GLOAD_LDS16(gB + (size_t)((hh)*128 + 64) * HDIM + G2_BOFF(ts),              \
                (dst) + ((hh)*128 + 64) * 64 + dofs); }
#define G2_RDA(src)                                                             \
  { _Pragma("unroll") for (int i_ = 0; i_ < 4; ++i_) {                          \
      const int rb_ = (wm * 64 + i_ * 16 + fr) << 6;                            \
      av[i_][0] = *(const bf16x8*)((src) + rb_ + so0);                          \
      av[i_][1] = *(const bf16x8*)((src) + rb_ + so1); } }
#define G2_RDB(src, NH)                                                         \
  { _Pragma("unroll") for (int n_ = 0; n_ < 2; ++n_) {                          \
      const int rb_ = ((NH)*128 + wn * 32 + n_ * 16 + fr) << 6;                 \
      bv[n_][0] = *(const bf16x8*)((src) + rb_ + so0);                          \
      bv[n_][1] = *(const bf16x8*)((src) + rb_ + so1); } }
#define G2_MMA(Q)                                                               \
  { __builtin_amdgcn_s_setprio(1);                                              \
    _Pragma("unroll") for (int i_ = 0; i_ < 4; ++i_)                            \
    _Pragma("unroll") for (int n_ = 0; n_ < 2; ++n_) {                          \
      acc[Q][i_][n_] = __builtin_amdgcn_mfma_f32_16x16x32_bf16(                 \
          av[i_][0], bv[n_][0], acc[Q][i_][n_], 0, 0, 0);                       \
      acc[Q][i_][n_] = __builtin_amdgcn_mfma_f32_16x16x32_bf16(                 \
          av[i_][1], bv[n_][1], acc[Q][i_][n_], 0, 0, 0); }                     \
    __builtin_amdgcn_s_setprio(0); }

  // prologue: tile0, issue order A,B0,B1 (matches steady state)
  G2_SA(aB0, 0); G2_SB(bB0, 0, 0); G2_SB(bB0, 1, 0);

  u16 *aC_ = aB0, *bC_ = bB0, *aN_ = aB1, *bN_ = bB1;

#pragma unroll 1
  for (int t = 0; t < G2_NKT; ++t) {
    const bool s1 = (t + 1 < G2_NKT);
    // p0 (N0): needs A(t),B0(t); stages A(t+1)+B0(t+1)
    VMW(2); ENTRYB();
    G2_RDA(aC_); G2_RDB(bC_, 0);
    if (s1) { G2_SA(aN_, t + 1); G2_SB(bN_, 0, t + 1); }
    LG0(); G2_MMA(0);
    // p1 (N1): needs B1(t); A reused in regs; stages B1(t+1)
    if (s1) { VMW(4); } else { VMW(0); }
    ENTRYB();
    G2_RDB(bC_, 1);
    if (s1) G2_SB(bN_, 1, t + 1);
    LG0(); G2_MMA(1);
    u16* tp;
    tp = aC_; aC_ = aN_; aN_ = tp;
    tp = bC_; bC_ = bN_; bN_ = tp;
  }

  // epilogue
  float b2c[2][2][NEXP];
  if (!accum) {
#pragma unroll
    for (int nh = 0; nh < 2; ++nh)
#pragma unroll
      for (int n = 0; n < 2; ++n)
#pragma unroll
        for (int e = 0; e < NEXP; ++e)
          b2c[nh][n][e] = bias[(size_t)e * DDIM + bn + nh * 128 + wn * 32 + n * 16 + fr];
  }
#pragma unroll
  for (int NH = 0; NH < 2; ++NH) {
    const int cb0 = bn + NH * 128 + wn * 32;
#pragma unroll
    for (int i = 0; i < 4; ++i) {
#pragma unroll
      for (int j = 0; j < 4; ++j) {
        const int r = bm + wm * 64 + i * 16 + fq * 4 + j;
        if (!accum) {
          float g8[NEXP];
#pragma unroll
          for (int e = 0; e < NEXP; ++e) g8[e] = gate[(size_t)r * NEXP + e];
#pragma unroll
          for (int n = 0; n < 2; ++n) {
            float v = acc[NH][i][n][j];
#pragma unroll
            for (int e = 0; e < NEXP; ++e) v += g8[e] * b2c[NH][n][e];
            Cout[(size_t)r * DDIM + cb0 + n * 16 + fr] = v;
          }
        } else {
#pragma unroll
          for (int n = 0; n < 2; ++n) {
            const size_t idx = (size_t)r * DDIM + cb0 + n * 16 + fr;
            Cout[idx] += acc[NH][i][n][j];
          }
        }
      }
    }
  }
#undef G2_BOFF
#undef G2_SA
#undef G2_SB
#undef G2_RDA
#undef G2_RDB
#undef G2_MMA
}

extern "C" void kernel_launch(void* const* d_in, const int* in_sizes, int n_in,
                              void* d_out, int out_size, void* d_ws, size_t ws_size,
                              hipStream_t stream) {
  (void)in_sizes; (void)n_in; (void)out_size;
  const float* x  = (const float*)d_in[0];   // [N, D]
  const float* W1 = (const float*)d_in[1];   // [E, D, H]
  const float* b1 = (const float*)d_in[2];   // [E, H]
  const float* W2 = (const float*)d_in[3];   // [E, H, D]
  const float* b2 = (const float*)d_in[4];   // [E, D]
  const float* Wg = (const float*)d_in[5];   // [D, E]
  const float* bg = (const float*)d_in[6];   // [E]
  float* out = (float*)d_out;                // [N, D]

  size_t o_xb   = 0;
  size_t o_w1t  = o_xb  + (size_t)NTOK * DDIM * 2;          // xb   bf16 [N,D]
  size_t o_w2t  = o_w1t + (size_t)NEXP * HDIM * DDIM * 2;   // W1t  bf16 [E*H, D]
  size_t o_gate = o_w2t + (size_t)NEXP * DDIM * HDIM * 2;   // W2t  bf16 [E][D][H]
  size_t o_h    = o_gate + (size_t)NTOK * NEXP * 4;         // gate f32  [N, E]
  size_t need   = o_h   + (size_t)NTOK * GEXP * HDIM * 2;   // h'   bf16 [N, G*H]
  if (ws_size < need) return;

  u16*   xb   = (u16*)((char*)d_ws + o_xb);
  u16*   W1t  = (u16*)((char*)d_ws + o_w1t);
  u16*   W2t  = (u16*)((char*)d_ws + o_w2t);
  float* gate = (float*)((char*)d_ws + o_gate);
  u16*   hbuf = (u16*)((char*)d_ws + o_h);

  k_prep<<<NTOK / 4, 256, 0, stream>>>(x, Wg, bg, xb, gate);
  dim3 g1(DDIM / 64, HDIM / 64, NEXP);
  k_transpose<<<g1, 256, 0, stream>>>(W1, W1t, DDIM, HDIM, (size_t)HDIM * DDIM, DDIM);
  dim3 g2(HDIM / 64, DDIM / 64, NEXP);
  k_transpose<<<g2, 256, 0, stream>>>(W2, W2t, HDIM, DDIM, (size_t)DDIM * HDIM, HDIM);

  const int Ng = GEXP * HDIM;                  // 4096
  for (int g = 0; g < NEXP / GEXP; ++g) {
    k_g1<<<512, 512, 0, stream>>>(
        xb, W1t + (size_t)g * Ng * DDIM,
        b1 + (size_t)g * Ng, gate, g * GEXP, hbuf);
    k_g2<<<256, 512, 0, stream>>>(
        hbuf, W2t + (size_t)g * GEXP * DDIM * HDIM,
        b2, gate, out, g > 0);
  }
}